// Round 6
// baseline (261.948 us; speedup 1.0000x reference)
//
#include <hip/hip_runtime.h>
#include <cstdint>
#include <cstddef>

// ---------------------------------------------------------------------------
// Threefry-2x32, 20 rounds, key = threefry_seed(42) = (0, 42)  (JAX-exact)
// ---------------------------------------------------------------------------
__device__ __forceinline__ uint32_t rotl32(uint32_t v, int d) {
  return (v << d) | (v >> (32 - d));
}

__device__ __forceinline__ void threefry2x32_seed42(uint32_t c0, uint32_t c1,
                                                    uint32_t& o0, uint32_t& o1) {
  const uint32_t ks0 = 0u;
  const uint32_t ks1 = 42u;
  const uint32_t ks2 = ks0 ^ ks1 ^ 0x1BD11BDAu;
  uint32_t x0 = c0 + ks0;
  uint32_t x1 = c1 + ks1;
#define TF_R(r) { x0 += x1; x1 = rotl32(x1, (r)); x1 ^= x0; }
  TF_R(13) TF_R(15) TF_R(26) TF_R(6)
  x0 += ks1; x1 += ks2 + 1u;
  TF_R(17) TF_R(29) TF_R(16) TF_R(24)
  x0 += ks2; x1 += ks0 + 2u;
  TF_R(13) TF_R(15) TF_R(26) TF_R(6)
  x0 += ks0; x1 += ks1 + 3u;
  TF_R(17) TF_R(29) TF_R(16) TF_R(24)
  x0 += ks1; x1 += ks2 + 4u;
  TF_R(13) TF_R(15) TF_R(26) TF_R(6)
  x0 += ks2; x1 += ks0 + 5u;
#undef TF_R
  o0 = x0; o1 = x1;
}

// JAX partitionable stream (default >= 0.5): counter = (0, f), bits = o0^o1.
__device__ __forceinline__ uint32_t jax_random_bits32(uint32_t f) {
  uint32_t o0, o1;
  threefry2x32_seed42(0u, f, o0, o1);
  return o0 ^ o1;
}

// Gumbel g = -log(-log(u)), fp32-rounded at each step (u pipeline bit-exact).
__device__ __forceinline__ float gumbel_f(uint32_t f) {
  const uint32_t bits = jax_random_bits32(f);
  const float base = __uint_as_float((bits >> 9) | 0x3F800000u) - 1.0f;
  const float u = fmaxf(1e-10f, __fadd_rn(base, 1e-10f));
  const float w = (float)(-log((double)u));
  const float g = (float)(-log((double)w));
  return g;
}

// ---------------------------------------------------------------------------
// int64-vs-int32 edge_index detection (indices < 50000 -> int64 high words 0).
// ---------------------------------------------------------------------------
__global__ void detect_idx_dtype(const unsigned long long* __restrict__ buf,
                                 int n64, int* __restrict__ flag) {
  __shared__ int cnt;
  if (threadIdx.x == 0) cnt = 0;
  __syncthreads();
  if ((int)threadIdx.x < n64) {
    if ((buf[threadIdx.x] >> 32) != 0ull) atomicAdd(&cnt, 1);
  }
  __syncthreads();
  if (threadIdx.x == 0) *flag = (cnt * 2 < n64) ? 1 : 0;  // 1 => int64
}

// ---------------------------------------------------------------------------
// LDS-transpose kernel. Block = 256 threads, CHUNK = 240 edges.
// Dot split into 4 segments of 32 elems. Per segment:
//   stage: 8 consecutive lanes load one row's 128B segment (coalesced lines),
//          write XOR-swizzled into LDS (physcol = j ^ ((row>>1)&7))
//   consume: thread t = edge t reads its 2 rows from LDS, continues the
//            strict-order fp32 chain (bit-identical to the R3 kernel).
// Register double-buffer: segment s+1's gathers issue before consuming s.
// ---------------------------------------------------------------------------
#define CHUNK 240
#define ROWS  480            // 2*CHUNK  (row = side*CHUNK + edge_in_chunk)
#define KPT   15             // (ROWS*8 float4-slots) / 256 threads

__global__ __launch_bounds__(256) void ipd_lds(
    const float* __restrict__ z1, const float* __restrict__ z2,
    const void* __restrict__ eidx, const int* __restrict__ flag64,
    float* __restrict__ out, int E) {
  __shared__ float4 sbuf[ROWS * 8];     // 60 KB
  __shared__ int sidx[2][CHUNK];        // 1.9 KB

  const int tid = threadIdx.x;
  const int cb  = blockIdx.x * CHUNK;
  const bool is64 = (*flag64 != 0);

  // ---- preload chunk edge indices into LDS
  if (tid < CHUNK) {
    const int ee = cb + tid;
    int i0 = 0, i1 = 0;
    if (ee < E) {
      if (is64) { const long long* p = (const long long*)eidx;
                  i0 = (int)p[ee]; i1 = (int)p[E + ee]; }
      else      { const int* p = (const int*)eidx;
                  i0 = p[ee]; i1 = p[E + ee]; }
    }
    sidx[0][tid] = i0;
    sidx[1][tid] = i1;
  }
  __syncthreads();

  // ---- per-thread constant staging descriptors (k is unroll-constant)
  const int myk = (tid >> 4) & 7;       // == ((row>>1)&7) for all my slots
  const float* srcp[KPT];
  int   waddr[KPT];
  bool  vld[KPT];
#pragma unroll
  for (int k = 0; k < KPT; ++k) {
    const int slot = tid + (k << 8);
    const int row  = slot >> 3;
    const int j    = slot & 7;
    const int side = (row >= CHUNK) ? 1 : 0;
    const int ec   = row - side * CHUNK;
    vld[k]   = (cb + ec) < E;
    srcp[k]  = z1 + (size_t)sidx[side][ec] * 128 + (j << 2);
    waddr[k] = (row << 3) + (j ^ myk);
  }

  const float4 fz4 = make_float4(0.f, 0.f, 0.f, 0.f);
  float4 vA[KPT], vB[KPT];

#define GATHER(V, S)                                                     \
  _Pragma("unroll")                                                      \
  for (int k = 0; k < KPT; ++k)                                          \
    V[k] = vld[k] ? *(const float4*)(srcp[k] + ((S) << 5)) : fz4;
#define WRITE(V)                                                         \
  _Pragma("unroll")                                                      \
  for (int k = 0; k < KPT; ++k) sbuf[waddr[k]] = V[k];

  // ---- issue segment-0 gathers, then RNG under their latency
  GATHER(vA, 0)

  const int e = cb + tid;
  float g0 = 0.f, g1 = 0.f;
  if (tid < CHUNK && e < E) {
    g0 = gumbel_f(2u * (uint32_t)e);
    g1 = gumbel_f(2u * (uint32_t)e + 1u);
  }

  float acc = 0.0f;
  const int kk = (tid >> 1) & 7;
  const int b0 = tid << 3;
  const int b1 = (CHUNK + tid) << 3;

#define CONSUME                                                          \
  if (tid < CHUNK && e < E) {                                            \
    _Pragma("unroll")                                                    \
    for (int j = 0; j < 8; ++j) {                                        \
      const float4 x = sbuf[b0 + (j ^ kk)];                              \
      const float4 y = sbuf[b1 + (j ^ kk)];                              \
      acc = __fadd_rn(acc, __fmul_rn(x.x, y.x));                         \
      acc = __fadd_rn(acc, __fmul_rn(x.y, y.y));                         \
      acc = __fadd_rn(acc, __fmul_rn(x.z, y.z));                         \
      acc = __fadd_rn(acc, __fmul_rn(x.w, y.w));                         \
    }                                                                    \
  }

  WRITE(vA)
  GATHER(vB, 1)                 // in flight during consume of seg 0
  __syncthreads();
  CONSUME
  __syncthreads();

  WRITE(vB)
  GATHER(vA, 2)
  __syncthreads();
  CONSUME
  __syncthreads();

  WRITE(vA)
  GATHER(vB, 3)
  __syncthreads();
  CONSUME
  __syncthreads();

  WRITE(vB)
  __syncthreads();
  CONSUME

#undef GATHER
#undef WRITE
#undef CONSUME

  // ---- decision + output (bit-identical to R3 logic)
  if (tid < CHUNK && e < E) {
    const int i0 = sidx[0][tid];
    const int i1 = sidx[1][tid];
    const float s0 = __fadd_rn(acc, g0);   // (vf + g0) / tau, tau == 1
    const float d  = __fsub_rn(s0, g1);
    bool a = (d >= 0.0f);
    if (!a) {
      a = ((float)exp((double)d) >= 1.0f); // softmax tie -> argmax 0 -> a=1
    }
    const float vn = __fadd_rn(z2[(size_t)i0 * 2], z2[(size_t)i1 * 2]);
    const float sf = 1.0f / (1.0f + expf(-acc));
    const float sn = 1.0f / (1.0f + expf(-vn));
    out[e] = a ? sf : sn;
  }
}

// ---------------------------------------------------------------------------
extern "C" void kernel_launch(void* const* d_in, const int* in_sizes, int n_in,
                              void* d_out, int out_size, void* d_ws, size_t ws_size,
                              hipStream_t stream) {
  const float* z1  = (const float*)d_in[0];
  const float* z2  = (const float*)d_in[1];
  const void* eidx = d_in[2];
  // d_in[3] = temp (==1); tau > 0 does not change the hard argmax.

  const int E = in_sizes[2] / 2;

  int* flag = (int*)d_ws;
  int n64 = E < 256 ? E : 256;
  hipLaunchKernelGGL(detect_idx_dtype, dim3(1), dim3(256), 0, stream,
                     (const unsigned long long*)eidx, n64, flag);

  const int blocks = (E + CHUNK - 1) / CHUNK;
  hipLaunchKernelGGL(ipd_lds, dim3(blocks), dim3(256), 0, stream,
                     z1, z2, eidx, flag, (float*)d_out, E);
}

// Round 7
// 101.119 us; speedup vs baseline: 2.5905x; 2.5905x over previous
//
#include <hip/hip_runtime.h>
#include <cstdint>
#include <cstddef>

// ---------------------------------------------------------------------------
// Threefry-2x32, 20 rounds, key = threefry_seed(42) = (0, 42)  (JAX-exact)
// ---------------------------------------------------------------------------
__device__ __forceinline__ uint32_t rotl32(uint32_t v, int d) {
  return (v << d) | (v >> (32 - d));
}

__device__ __forceinline__ void threefry2x32_seed42(uint32_t c0, uint32_t c1,
                                                    uint32_t& o0, uint32_t& o1) {
  const uint32_t ks0 = 0u;
  const uint32_t ks1 = 42u;
  const uint32_t ks2 = ks0 ^ ks1 ^ 0x1BD11BDAu;
  uint32_t x0 = c0 + ks0;
  uint32_t x1 = c1 + ks1;
#define TF_R(r) { x0 += x1; x1 = rotl32(x1, (r)); x1 ^= x0; }
  TF_R(13) TF_R(15) TF_R(26) TF_R(6)
  x0 += ks1; x1 += ks2 + 1u;
  TF_R(17) TF_R(29) TF_R(16) TF_R(24)
  x0 += ks2; x1 += ks0 + 2u;
  TF_R(13) TF_R(15) TF_R(26) TF_R(6)
  x0 += ks0; x1 += ks1 + 3u;
  TF_R(17) TF_R(29) TF_R(16) TF_R(24)
  x0 += ks1; x1 += ks2 + 4u;
  TF_R(13) TF_R(15) TF_R(26) TF_R(6)
  x0 += ks2; x1 += ks0 + 5u;
#undef TF_R
  o0 = x0; o1 = x1;
}

// JAX partitionable stream (default >= 0.5): counter = (0, f), bits = o0^o1.
__device__ __forceinline__ uint32_t jax_random_bits32(uint32_t f) {
  uint32_t o0, o1;
  threefry2x32_seed42(0u, f, o0, o1);
  return o0 ^ o1;
}

// Gumbel g = -log(-log(u)), fp32-rounded at each step (u pipeline bit-exact).
__device__ __forceinline__ float gumbel_f(uint32_t f) {
  const uint32_t bits = jax_random_bits32(f);
  const float base = __uint_as_float((bits >> 9) | 0x3F800000u) - 1.0f;
  const float u = fmaxf(1e-10f, __fadd_rn(base, 1e-10f));
  const float w = (float)(-log((double)u));
  const float g = (float)(-log((double)w));
  return g;
}

// ---------------------------------------------------------------------------
// int64-vs-int32 edge_index detection (indices < 50000 -> int64 high words 0).
// ---------------------------------------------------------------------------
__global__ void detect_idx_dtype(const unsigned long long* __restrict__ buf,
                                 int n64, int* __restrict__ flag) {
  __shared__ int cnt;
  if (threadIdx.x == 0) cnt = 0;
  __syncthreads();
  if ((int)threadIdx.x < n64) {
    if ((buf[threadIdx.x] >> 32) != 0ull) atomicAdd(&cnt, 1);
  }
  __syncthreads();
  if (threadIdx.x == 0) *flag = (cnt * 2 < n64) ? 1 : 0;  // 1 => int64
}

// ---------------------------------------------------------------------------
// One WAVE (= one 64-thread block) handles 64 edges. Dot over D=128 split
// into 4 segments of 32 floats (128B per row).
//   stage:   lane L loads 16 slots; 8 consecutive lanes cover one row's 128B
//            -> 8 line-transactions per wave-instruction (vs 64 divergent).
//   LDS:     [128 rows][8 float4], column swizzled col ^ ((row>>1)&7):
//            both ds_write and ds_read are bank-even (8 words/bank / 1KB).
//   consume: lane e = edge e reads rows 2e, 2e+1 in ascending j ->
//            strict-order fp32 chain, bit-identical to the R3 kernel.
//   pipeline: register prefetch of segment s+1 overlaps consume of s;
//            single wave per block -> lockstep, NO barriers needed.
// ---------------------------------------------------------------------------
__global__ __launch_bounds__(64) void ipd_wave(
    const float* __restrict__ z1, const float* __restrict__ z2,
    const void* __restrict__ eidx, const int* __restrict__ flag64,
    float* __restrict__ out, int E) {
  __shared__ float4 sbuf[1024];   // 16 KB: [128][8], col-swizzled
  __shared__ int    sidx[128];    // row -> z1 row index (2e: i0, 2e+1: i1)

  const int lane = threadIdx.x;
  const long long e = (long long)blockIdx.x * 64 + lane;
  const bool valid = e < E;
  const bool is64 = (*flag64 != 0);

  int i0 = 0, i1 = 0;
  if (valid) {
    if (is64) { const long long* p = (const long long*)eidx;
                i0 = (int)p[e]; i1 = (int)p[E + e]; }
    else      { const int* p = (const int*)eidx;
                i0 = p[e]; i1 = p[E + e]; }
  }
  sidx[2 * lane]     = i0;
  sidx[2 * lane + 1] = i1;
  __syncthreads();   // single-wave block: effectively free

  // per-lane staging descriptors: 16 slots (slot = k*64 + lane)
  unsigned soff[16];
  int wa[16];
#pragma unroll
  for (int k = 0; k < 16; ++k) {
    const int r = (k << 3) + (lane >> 3);      // row 0..127
    soff[k] = (unsigned)sidx[r] * 512u + (unsigned)((lane & 7) << 4);
    wa[k]   = (r << 3) + ((lane & 7) ^ ((r >> 1) & 7));
  }

  const char* zb = (const char*)z1;
  float4 v[16];

#define GATHER(S)                                              \
  _Pragma("unroll")                                            \
  for (int k = 0; k < 16; ++k)                                 \
    v[k] = *(const float4*)(zb + soff[k] + ((S) << 7));
#define WRITE()                                                \
  _Pragma("unroll")                                            \
  for (int k = 0; k < 16; ++k) sbuf[wa[k]] = v[k];

  GATHER(0)

  // RNG + z2 gather hide under segment-0 global latency
  float g0 = 0.f, g1 = 0.f, z2a = 0.f, z2b = 0.f;
  if (valid) {
    g0  = gumbel_f(2u * (uint32_t)e);
    g1  = gumbel_f(2u * (uint32_t)e + 1u);
    z2a = z2[(size_t)i0 * 2];
    z2b = z2[(size_t)i1 * 2];
  }

  float acc = 0.0f;
  const int b0 = lane << 4;        // row 2*lane   -> slot base (2*lane)*8
  const int b1 = b0 + 8;           // row 2*lane+1
  const int sw = lane & 7;         // swizzle key for both rows

#define CONSUME                                                \
  { _Pragma("unroll")                                          \
    for (int j = 0; j < 8; ++j) {                              \
      const float4 x = sbuf[b0 + (j ^ sw)];                    \
      const float4 y = sbuf[b1 + (j ^ sw)];                    \
      acc = __fadd_rn(acc, __fmul_rn(x.x, y.x));               \
      acc = __fadd_rn(acc, __fmul_rn(x.y, y.y));               \
      acc = __fadd_rn(acc, __fmul_rn(x.z, y.z));               \
      acc = __fadd_rn(acc, __fmul_rn(x.w, y.w));               \
    } }

  WRITE()        // seg 0 into LDS
  GATHER(1)      // seg 1 loads in flight during consume of seg 0
  CONSUME        // seg 0
  WRITE()        // seg 1
  GATHER(2)
  CONSUME        // seg 1
  WRITE()        // seg 2
  GATHER(3)
  CONSUME        // seg 2
  WRITE()        // seg 3
  CONSUME        // seg 3

#undef GATHER
#undef WRITE
#undef CONSUME

  if (valid) {
    const float s0 = __fadd_rn(acc, g0);   // (vf + g0) / tau, tau == 1
    const float d  = __fsub_rn(s0, g1);
    bool a = (d >= 0.0f);
    if (!a) {
      a = ((float)exp((double)d) >= 1.0f); // softmax tie -> argmax 0 -> a=1
    }
    const float vn = __fadd_rn(z2a, z2b);
    const float sf = 1.0f / (1.0f + expf(-acc));
    const float sn = 1.0f / (1.0f + expf(-vn));
    out[e] = a ? sf : sn;
  }
}

// ---------------------------------------------------------------------------
extern "C" void kernel_launch(void* const* d_in, const int* in_sizes, int n_in,
                              void* d_out, int out_size, void* d_ws, size_t ws_size,
                              hipStream_t stream) {
  const float* z1  = (const float*)d_in[0];
  const float* z2  = (const float*)d_in[1];
  const void* eidx = d_in[2];
  // d_in[3] = temp (==1); tau > 0 does not change the hard argmax.

  const int E = in_sizes[2] / 2;

  int* flag = (int*)d_ws;
  int n64 = E < 256 ? E : 256;
  hipLaunchKernelGGL(detect_idx_dtype, dim3(1), dim3(256), 0, stream,
                     (const unsigned long long*)eidx, n64, flag);

  const int blocks = (E + 63) / 64;
  hipLaunchKernelGGL(ipd_wave, dim3(blocks), dim3(64), 0, stream,
                     z1, z2, eidx, flag, (float*)d_out, E);
}